// Round 12
// baseline (1768.653 us; speedup 1.0000x reference)
//
#include <hip/hip_runtime.h>
#include <hip/hip_bf16.h>
#include <cstddef>

#define BATCH 16
#define TSTEPS 128
#define MSLOTS 512
#define DIN 256
#define UNITS 256
#define ZDIM 1024
#define G 8          // blocks per batch
#define NBLK (BATCH*G)
#define NTHR 1024

static __device__ __forceinline__ float tanhf_fast(float x) {
    float e = __expf(2.0f * x);
    return 1.0f - 2.0f / (e + 1.0f);
}
static __device__ __forceinline__ float sigmoidf_fast(float x) {
    return 1.0f / (1.0f + __expf(-x));
}
static __device__ __forceinline__ void st_agent_u(unsigned* p, unsigned v) {
    __hip_atomic_store(p, v, __ATOMIC_RELAXED, __HIP_MEMORY_SCOPE_AGENT);
}
static __device__ __forceinline__ unsigned ld_agent_u(const unsigned* p) {
    return __hip_atomic_load(p, __ATOMIC_RELAXED, __HIP_MEMORY_SCOPE_AGENT);
}
// Poll a tagged word until low byte == tag; return value with tag cleared.
static __device__ __forceinline__ float poll_tag(const unsigned* p, unsigned tag) {
    unsigned w = ld_agent_u(p);
    while ((w & 0xFFu) != tag) {
        __builtin_amdgcn_s_sleep(1);
        w = ld_agent_u(p);
    }
    return __uint_as_float(w & 0xFFFFFF00u);
}
// pack two f32 -> bf16 pair (rne); lo = a, hi = b
static __device__ __forceinline__ unsigned pack_bf(float a, float b) {
    unsigned ua = __float_as_uint(a); ua = (ua + 0x7fffu + ((ua >> 16) & 1u)) >> 16;
    unsigned ub = __float_as_uint(b); ub = ((ub + 0x7fffu + ((ub >> 16) & 1u)) >> 16) << 16;
    return ua | ub;
}
static __device__ __forceinline__ float bf_lo(unsigned w) { return __uint_as_float(w << 16); }
static __device__ __forceinline__ float bf_hi(unsigned w) { return __uint_as_float(w & 0xffff0000u); }

// ---------------------------------------------------------------------------
// f32 GEMM + bias: C[M][N] = A @ B + bias. 64x64 tile, 256 thr, 4x4/thread.
// ---------------------------------------------------------------------------
__global__ __launch_bounds__(256) void gemm_bias_kernel(
    const float* __restrict__ A, const float* __restrict__ B,
    const float* __restrict__ bias, float* __restrict__ C,
    int M, int N, int K)
{
    __shared__ float As[16][68];
    __shared__ float Bs[16][68];
    const int tid = threadIdx.x;
    const int bm = blockIdx.x * 64;
    const int bn = blockIdx.y * 64;
    const int tx = tid & 15, ty = tid >> 4;
    const int ar = tid >> 2, ac = (tid & 3) * 4;
    const int br = tid >> 4, bc = (tid & 15) * 4;
    float acc[4][4] = {};

    for (int k0 = 0; k0 < K; k0 += 16) {
        float4 av = *(const float4*)(A + (size_t)(bm + ar) * K + k0 + ac);
        float4 bv = *(const float4*)(B + (size_t)(k0 + br) * N + bn + bc);
        As[ac + 0][ar] = av.x; As[ac + 1][ar] = av.y;
        As[ac + 2][ar] = av.z; As[ac + 3][ar] = av.w;
        *(float4*)(&Bs[br][bc]) = bv;
        __syncthreads();
#pragma unroll
        for (int kk = 0; kk < 16; ++kk) {
            float a0 = As[kk][ty*4+0], a1 = As[kk][ty*4+1];
            float a2 = As[kk][ty*4+2], a3 = As[kk][ty*4+3];
            float b0 = Bs[kk][tx*4+0], b1 = Bs[kk][tx*4+1];
            float b2 = Bs[kk][tx*4+2], b3 = Bs[kk][tx*4+3];
            acc[0][0]+=a0*b0; acc[0][1]+=a0*b1; acc[0][2]+=a0*b2; acc[0][3]+=a0*b3;
            acc[1][0]+=a1*b0; acc[1][1]+=a1*b1; acc[1][2]+=a1*b2; acc[1][3]+=a1*b3;
            acc[2][0]+=a2*b0; acc[2][1]+=a2*b1; acc[2][2]+=a2*b2; acc[2][3]+=a2*b3;
            acc[3][0]+=a3*b0; acc[3][1]+=a3*b1; acc[3][2]+=a3*b2; acc[3][3]+=a3*b3;
        }
        __syncthreads();
    }
#pragma unroll
    for (int i = 0; i < 4; ++i)
#pragma unroll
        for (int j = 0; j < 4; ++j) {
            int cn = bn + tx * 4 + j;
            C[(size_t)(bm + ty * 4 + i) * N + cn] = acc[i][j] + bias[cn];
        }
}

// ---------------------------------------------------------------------------
// GEMM, no bias, bf16 output, per-batch TRANSPOSED store: CT[b][n][m] ushort.
// A rows are batch-major (512 rows per batch). Used for AW2 = attended @ W2.
// ---------------------------------------------------------------------------
__global__ __launch_bounds__(256) void gemm_T_bf16_kernel(
    const float* __restrict__ A, const float* __restrict__ B,
    unsigned short* __restrict__ CT, int M, int N, int K)
{
    __shared__ float As[16][68];
    __shared__ float Bs[16][68];
    __shared__ float Ts[64][65];
    const int tid = threadIdx.x;
    const int bm = blockIdx.x * 64;
    const int bn = blockIdx.y * 64;
    const int tx = tid & 15, ty = tid >> 4;
    const int ar = tid >> 2, ac = (tid & 3) * 4;
    const int br = tid >> 4, bc = (tid & 15) * 4;
    float acc[4][4] = {};

    for (int k0 = 0; k0 < K; k0 += 16) {
        float4 av = *(const float4*)(A + (size_t)(bm + ar) * K + k0 + ac);
        float4 bv = *(const float4*)(B + (size_t)(k0 + br) * N + bn + bc);
        As[ac + 0][ar] = av.x; As[ac + 1][ar] = av.y;
        As[ac + 2][ar] = av.z; As[ac + 3][ar] = av.w;
        *(float4*)(&Bs[br][bc]) = bv;
        __syncthreads();
#pragma unroll
        for (int kk = 0; kk < 16; ++kk) {
            float a0 = As[kk][ty*4+0], a1 = As[kk][ty*4+1];
            float a2 = As[kk][ty*4+2], a3 = As[kk][ty*4+3];
            float b0 = Bs[kk][tx*4+0], b1 = Bs[kk][tx*4+1];
            float b2 = Bs[kk][tx*4+2], b3 = Bs[kk][tx*4+3];
            acc[0][0]+=a0*b0; acc[0][1]+=a0*b1; acc[0][2]+=a0*b2; acc[0][3]+=a0*b3;
            acc[1][0]+=a1*b0; acc[1][1]+=a1*b1; acc[1][2]+=a1*b2; acc[1][3]+=a1*b3;
            acc[2][0]+=a2*b0; acc[2][1]+=a2*b1; acc[2][2]+=a2*b2; acc[2][3]+=a2*b3;
            acc[3][0]+=a3*b0; acc[3][1]+=a3*b1; acc[3][2]+=a3*b2; acc[3][3]+=a3*b3;
        }
        __syncthreads();
    }
#pragma unroll
    for (int i = 0; i < 4; ++i)
#pragma unroll
        for (int j = 0; j < 4; ++j)
            Ts[tx * 4 + j][ty * 4 + i] = acc[i][j];
    __syncthreads();
    const int jr = tid >> 2, ms2 = (tid & 3) * 16;
    const int b = bm >> 9, m0 = bm & 511;
    unsigned short* dst = CT + (size_t)b * ((size_t)N * 512)
                        + (size_t)(bn + jr) * 512 + m0 + ms2;
#pragma unroll
    for (int u = 0; u < 16; ++u) {
        unsigned ua = __float_as_uint(Ts[jr][ms2 + u]);
        ua = (ua + 0x7fffu + ((ua >> 16) & 1u)) >> 16;
        dst[u] = (unsigned short)ua;
    }
}

// ---------------------------------------------------------------------------
// Persistent scan: 128 blocks (8 per batch), 1024 threads, 2 TAGGED exchanges
// (one UC round-trip each: tag rides in the low 8 mantissa bits; consumer
// lanes poll their own data word -- no sentinel, no drain, no second trip).
// Block (b,g): m-slice 64 slots (scores), col-slice 128 z-cols; gates for own
// 32 units. zc computed once per col from gathered p via AW2 slice in LDS.
// Regs: wq 32 + keys 8 + u 16 = 56 u32 (R11 compiled VGPR=64, no spills).
// p tags odd (2t+1), h tags even (2t+2), mod 256; buffers memset 0xFF
// in-graph each launch -> unique within launch, replay-safe.
// ---------------------------------------------------------------------------
__global__ __launch_bounds__(NTHR, 4) void rnn_persistent(
    const float* __restrict__ query_W, const float* __restrict__ query_b,
    const float* __restrict__ attn_W,  const float* __restrict__ lstm_U,
    const float* __restrict__ keys,    const float* __restrict__ pre,
    const unsigned short* __restrict__ aw2T,
    unsigned* pB, unsigned* hB,
    float* __restrict__ seq, float* __restrict__ hT, float* __restrict__ cT)
{
    const int bid = blockIdx.x;
    const int b = bid >> 3, g = bid & 7;
    const int tid = threadIdx.x;

    __shared__ unsigned aw2L[256 * 128];   // 128 KB: AW2[m-pair][own col] bf16 pairs
    __shared__ __align__(16) float h_s[256];
    __shared__ __align__(16) float q_s[256];
    __shared__ __align__(16) float qp_s[4][256];
    __shared__ __align__(16) float p_s[512];
    __shared__ __align__(16) float pown_s[64];
    __shared__ __align__(16) float zp_s[8][128];
    __shared__ __align__(16) float z_s[128];
    __shared__ __align__(16) float aw_s[256];
    __shared__ __align__(16) float qb_s[256];
    __shared__ __align__(16) float red_s[8];

    // roles
    const int jq = tid & 255, kq = tid >> 8;     // q: col jq, k-quarter kq
    const int mloc = tid >> 4, jc = tid & 15;    // scores: own m, j-comb jc
    const int cc = tid & 127, ks = tid >> 7;     // z: own col cc, m/k-slice ks
    const int col_own = ((cc >> 5) << 8) + g * 32 + (cc & 31);

    // ---- prologue: AW2 own-col slice -> LDS (pairs along m) ----
    for (int i = tid; i < 256 * 128; i += NTHR) {
        int pr = i >> 7, c2 = i & 127;
        int colc = ((c2 >> 5) << 8) + g * 32 + (c2 & 31);
        aw2L[i] = ((const unsigned*)(aw2T + ((size_t)b * ZDIM + colc) * 512))[pr];
    }
    // Wq in registers: Wq[kq*64 + 2i(+1)][jq] pairs along k
    unsigned wq_r[32];
#pragma unroll
    for (int i = 0; i < 32; ++i)
        wq_r[i] = pack_bf(query_W[(size_t)(kq * 64 + 2 * i) * 256 + jq],
                          query_W[(size_t)(kq * 64 + 2 * i + 1) * 256 + jq]);
    // keys own m-row, interleaved j (j = jc+32i and jc+32i+16), bf16 pairs
    unsigned keys_r[8];
    {
        const float* krow = keys + (size_t)(b * MSLOTS + g * 64 + mloc) * 256;
#pragma unroll
        for (int i = 0; i < 8; ++i)
            keys_r[i] = pack_bf(krow[jc + 32 * i], krow[jc + 32 * i + 16]);
    }
    // U k-slice for own col (pairs along k)
    unsigned u_r[16];
#pragma unroll
    for (int i = 0; i < 16; ++i)
        u_r[i] = pack_bf(lstm_U[(size_t)(ks * 32 + 2 * i) * ZDIM + col_own],
                         lstm_U[(size_t)(ks * 32 + 2 * i + 1) * ZDIM + col_own]);

    if (tid < 256) {
        aw_s[tid] = attn_W[tid];
        qb_s[tid] = query_b[tid];
        h_s[tid] = 0.0f;
    }
    float c_r = 0.0f;   // cell state for unit g*32 + tid (tid<32)
    __syncthreads();

    const float* preb = pre + (size_t)b * TSTEPS * ZDIM;
    unsigned* pBb = pB + b * 512;
    unsigned* hBb = hB + b * 256;

    for (int t = 0; t < TSTEPS; ++t) {
        const unsigned ptag = (unsigned)((2 * t + 1) & 0xFF);   // odd
        const unsigned htag = (unsigned)((2 * t + 2) & 0xFF);   // even

        float pre_r = 0.0f;
        if (tid < 128)
            pre_r = preb[(size_t)t * ZDIM + col_own];

        // ---- phase Q: q partials from registers ----
        {
            float qa = 0.0f;
#pragma unroll
            for (int i = 0; i < 32; ++i) {
                float2 hv = *(const float2*)&h_s[kq * 64 + 2 * i];
                qa += hv.x * bf_lo(wq_r[i]) + hv.y * bf_hi(wq_r[i]);
            }
            qp_s[kq][jq] = qa;
        }
        __syncthreads();
        if (tid < 256)
            q_s[tid] = qb_s[tid] + qp_s[0][tid] + qp_s[1][tid] + qp_s[2][tid] + qp_s[3][tid];
        __syncthreads();

        // ---- phase S: scores + exp; TAGGED publish immediately ----
        {
            float sacc = 0.0f;
#pragma unroll
            for (int i = 0; i < 8; ++i) {
                int j0 = jc + 32 * i, j1 = j0 + 16;
                unsigned kw = keys_r[i];
                sacc += aw_s[j0] * tanhf_fast(bf_lo(kw) + q_s[j0]);
                sacc += aw_s[j1] * tanhf_fast(bf_hi(kw) + q_s[j1]);
            }
            sacc += __shfl_xor(sacc, 1);
            sacc += __shfl_xor(sacc, 2);
            sacc += __shfl_xor(sacc, 4);
            sacc += __shfl_xor(sacc, 8);
            if (jc == 0) {
                float pv = __expf(sacc);                // |s| <= ~13, no max-sub
                unsigned w = (__float_as_uint(pv) & 0xFFFFFF00u) | ptag;
                pown_s[mloc] = __uint_as_float(w & 0xFFFFFF00u);
                st_agent_u(&pBb[g * 64 + mloc], w);     // data-is-flag, one RT
            }
        }

        // ---- zh partials from registers (hides p propagation) ----
        {
            float zh = 0.0f;
#pragma unroll
            for (int i = 0; i < 16; ++i) {
                float2 hv = *(const float2*)&h_s[ks * 32 + 2 * i];
                zh += hv.x * bf_lo(u_r[i]) + hv.y * bf_hi(u_r[i]);
            }
            zp_s[ks][cc] = zh;
        }
        __syncthreads();

        // ---- zv = pre + zh (register, tid<128); gather p (poll own word) ----
        float zv = 0.0f;
        if (tid < 128)
            zv = pre_r + zp_s[0][cc] + zp_s[1][cc] + zp_s[2][cc] + zp_s[3][cc]
               + zp_s[4][cc] + zp_s[5][cc] + zp_s[6][cc] + zp_s[7][cc];
        if (tid < 512) {
            float pv;
            if ((tid >> 6) == g) pv = pown_s[tid & 63];
            else                 pv = poll_tag(&pBb[tid], ptag);
            p_s[tid] = pv;
            float dv = pv;
            dv += __shfl_xor(dv, 1);  dv += __shfl_xor(dv, 2);  dv += __shfl_xor(dv, 4);
            dv += __shfl_xor(dv, 8);  dv += __shfl_xor(dv, 16); dv += __shfl_xor(dv, 32);
            if ((tid & 63) == 0) red_s[tid >> 6] = dv;
        }
        __syncthreads();
        float inv;
        {
            float tot = red_s[0] + red_s[1] + red_s[2] + red_s[3]
                      + red_s[4] + red_s[5] + red_s[6] + red_s[7];
            inv = 1.0f / tot;
        }

        // ---- phase Z: zc for own col from LDS AW2 ----
        {
            float zc = 0.0f;
#pragma unroll
            for (int i = 0; i < 32; ++i) {
                float2 pv = *(const float2*)&p_s[ks * 64 + 2 * i];
                unsigned w = aw2L[(ks * 32 + i) * 128 + cc];
                zc += pv.x * bf_lo(w) + pv.y * bf_hi(w);
            }
            zp_s[ks][cc] = zc;
        }
        __syncthreads();
        if (tid < 128) {
            float zcs = zp_s[0][cc] + zp_s[1][cc] + zp_s[2][cc] + zp_s[3][cc]
                      + zp_s[4][cc] + zp_s[5][cc] + zp_s[6][cc] + zp_s[7][cc];
            z_s[cc] = zv + zcs * inv;
        }
        __syncthreads();

        // ---- gates + state for own 32 units; TAGGED h publish ----
        if (tid < 32) {
            float zi = z_s[tid], zf = z_s[32 + tid], zg = z_s[64 + tid], zo = z_s[96 + tid];
            float ig = sigmoidf_fast(zi);
            float fg = sigmoidf_fast(zf);
            float gg = tanhf_fast(zg);
            float og = sigmoidf_fast(zo);
            float cn = fg * c_r + ig * gg;
            float hn = og * tanhf_fast(cn);
            c_r = cn;
            unsigned w = (__float_as_uint(hn) & 0xFFFFFF00u) | htag;
            float hn_t = __uint_as_float(w & 0xFFFFFF00u);
            int u = g * 32 + tid;
            h_s[u] = hn_t;
            st_agent_u(&hBb[u], w);                     // data-is-flag, one RT
            seq[((size_t)b * TSTEPS + t) * UNITS + u] = hn_t;
            if (t == TSTEPS - 1) { hT[b * UNITS + u] = hn_t; cT[b * UNITS + u] = cn; }
        }

        // ---- gather h (poll own word; own slice already in h_s) ----
        if (tid < 256 && (tid >> 5) != g)
            h_s[tid] = poll_tag(&hBb[tid], htag);
        __syncthreads();
    }
}

// ---------------------------------------------------------------------------
extern "C" void kernel_launch(void* const* d_in, const int* in_sizes, int n_in,
                              void* d_out, int out_size, void* d_ws, size_t ws_size,
                              hipStream_t stream)
{
    (void)in_sizes; (void)n_in; (void)out_size; (void)ws_size;
    const float* inputs   = (const float*)d_in[0];
    const float* attended = (const float*)d_in[1];
    const float* key_W    = (const float*)d_in[2];
    const float* key_b    = (const float*)d_in[3];
    const float* query_W  = (const float*)d_in[4];
    const float* query_b  = (const float*)d_in[5];
    const float* attn_W   = (const float*)d_in[6];
    const float* lstm_W   = (const float*)d_in[8];
    const float* lstm_U   = (const float*)d_in[9];
    const float* lstm_b   = (const float*)d_in[10];
    // attn_b (d_in[7]) cancels in softmax — dropped.

    float* out = (float*)d_out;
    float* seq = out;
    float* hT  = out + (size_t)BATCH * TSTEPS * UNITS;
    float* cT  = hT + BATCH * UNITS;

    float* ws = (float*)d_ws;
    float* keys = ws;                                        // 2,097,152 f
    float* pre  = keys + 2097152;                            // 2,097,152 f
    unsigned short* aw2T = (unsigned short*)(pre + 2097152); // 16*1024*512 ushort
    unsigned* pB = (unsigned*)(aw2T + (size_t)16 * 1024 * 512); // 16*512 u32
    unsigned* hB = pB + BATCH * 512;                            // 16*256 u32

    // tagged comm words -> 0xFF (tag byte never 1..128's sequence values
    // match 0xFF) each launch; in-graph memset makes replays safe
    hipMemsetAsync(pB, 0xFF, (size_t)BATCH * (512 + 256) * sizeof(unsigned), stream);

    // keys = attended @ key_W + key_b          (8192 x 256)
    gemm_bias_kernel<<<dim3(128, 4), 256, 0, stream>>>(
        attended, key_W, key_b, keys, 8192, 256, 256);
    // pre = inputs @ lstm_W[:256] + lstm_b     (2048 x 1024)
    gemm_bias_kernel<<<dim3(32, 16), 256, 0, stream>>>(
        inputs, lstm_W, lstm_b, pre, 2048, 1024, 256);
    // AW2^T (bf16) = (attended @ lstm_W[256:])^T per batch: [b][1024][512]
    gemm_T_bf16_kernel<<<dim3(128, 16), 256, 0, stream>>>(
        attended, lstm_W + (size_t)256 * ZDIM, aw2T, 8192, 1024, 256);

    rnn_persistent<<<dim3(NBLK), dim3(NTHR), 0, stream>>>(
        query_W, query_b, attn_W, lstm_U,
        keys, pre, aw2T, pB, hB, seq, hT, cT);
}